// Round 4
// baseline (2948.080 us; speedup 1.0000x reference)
//
#include <hip/hip_runtime.h>

// ---------------------------------------------------------------------------
// 2-layer GRU, B=64 S=2048 IN=208 H=100 OUT=98, fp32.
//   gemm_bias:  xg0 = seq @ w_ih_l0^T + b_ih_l0          (full-GPU GEMM)
//   gru_fused:  128 persistent blocks (64 producer = layer0, 64 consumer).
// R4 step structure (ONE barrier per step, no gate LDS round-trip):
//   lane mapping: wave w, lanes 6*jl+{0..5} own h-index j=10w+jl; roles
//   r/z/n × k-halves. After pair-sum shfl, gate lane (role r, even) gathers
//   zpre/hn via 2 shfls and computes h_j fully in-register -> hs[nxt][j].
//   hs is double-buffered so dot reads of h_{t-1} never race h_t writes.
//   dot2 (w_ih1·h -> ring | w_out·h -> out) reads the stable buffer with a
//   1-step lag. Global stores stay in flight across lgkm-only barriers;
//   full drain only at producer publish points (every KPUB steps).
// ---------------------------------------------------------------------------

#define GB_BM 64
#define GB_BN 64
#define GB_BK 16

__global__ __launch_bounds__(256)
void gemm_bias(const float* __restrict__ A, const float* __restrict__ W,
               const float* __restrict__ bias, float* __restrict__ C,
               int Sc, long a_bs, long a_ss, long c_bs, long c_ss,
               int N, int K)
{
    __shared__ float As[GB_BK][68];
    __shared__ float Bs[GB_BK][68];
    const int tid = threadIdx.x;
    const int m0 = blockIdx.x * GB_BM;
    const int n0 = blockIdx.y * GB_BN;

    const int lm = tid >> 2;
    const int lk = (tid & 3) << 2;
    const int row = m0 + lm;
    const float* arow = A + (long)(row / Sc) * a_bs + (long)(row % Sc) * a_ss;
    const int wrow = n0 + lm;
    const float* wrp = W + (long)wrow * K;
    const bool wv_ok = (wrow < N);

    const int tx = tid & 15;
    const int ty = tid >> 4;

    float acc[4][4] = {};

    for (int k0 = 0; k0 < K; k0 += GB_BK) {
        float4 av, bv;
        if (k0 + GB_BK <= K) {
            av = *(const float4*)(arow + k0 + lk);
            bv = wv_ok ? *(const float4*)(wrp + k0 + lk) : make_float4(0.f,0.f,0.f,0.f);
        } else {
            av = make_float4(0.f,0.f,0.f,0.f);
            bv = make_float4(0.f,0.f,0.f,0.f);
            const int kb = k0 + lk;
            if (kb + 0 < K) { av.x = arow[kb+0]; if (wv_ok) bv.x = wrp[kb+0]; }
            if (kb + 1 < K) { av.y = arow[kb+1]; if (wv_ok) bv.y = wrp[kb+1]; }
            if (kb + 2 < K) { av.z = arow[kb+2]; if (wv_ok) bv.z = wrp[kb+2]; }
            if (kb + 3 < K) { av.w = arow[kb+3]; if (wv_ok) bv.w = wrp[kb+3]; }
        }
        As[lk+0][lm] = av.x; As[lk+1][lm] = av.y; As[lk+2][lm] = av.z; As[lk+3][lm] = av.w;
        Bs[lk+0][lm] = bv.x; Bs[lk+1][lm] = bv.y; Bs[lk+2][lm] = bv.z; Bs[lk+3][lm] = bv.w;
        __syncthreads();
        #pragma unroll
        for (int kk = 0; kk < GB_BK; kk++) {
            float4 a  = *(const float4*)&As[kk][ty << 2];
            float4 bb = *(const float4*)&Bs[kk][tx << 2];
            float ar[4] = {a.x, a.y, a.z, a.w};
            float br[4] = {bb.x, bb.y, bb.z, bb.w};
            #pragma unroll
            for (int i = 0; i < 4; i++)
                #pragma unroll
                for (int j = 0; j < 4; j++)
                    acc[i][j] += ar[i] * br[j];
        }
        __syncthreads();
    }

    #pragma unroll
    for (int i = 0; i < 4; i++) {
        const int r = m0 + (ty << 2) + i;
        float* crow = C + (long)(r / Sc) * c_bs + (long)(r % Sc) * c_ss;
        #pragma unroll
        for (int j = 0; j < 4; j++) {
            const int col = n0 + (tx << 2) + j;
            if (col < N) crow[col] = acc[i][j] + bias[col];
        }
    }
}

// ---------------------------------------------------------------------------

#define RING_W 256   // ring depth in timesteps (power of 2), per batch
#define KPUB   16    // flag publish / wait granularity (power of 2)

__device__ __forceinline__ float fsig(float x)  { return 1.f / (1.f + __expf(-x)); }
__device__ __forceinline__ float ftanh(float x) { return 1.f - 2.f / (1.f + __expf(2.f * x)); }

__device__ __forceinline__ void bar_lgkm() {
    asm volatile("s_waitcnt lgkmcnt(0)" ::: "memory");
    __builtin_amdgcn_sched_barrier(0);
    __builtin_amdgcn_s_barrier();
}
__device__ __forceinline__ void bar_full() {
    asm volatile("s_waitcnt vmcnt(0) lgkmcnt(0)" ::: "memory");
    __builtin_amdgcn_sched_barrier(0);
    __builtin_amdgcn_s_barrier();
}
// Bounded spin: a protocol bug shows as a wrong result, not a dead container.
__device__ __forceinline__ void wait_ge(int* p, int tgt) {
    int spins = 0;
    while (__hip_atomic_load(p, __ATOMIC_ACQUIRE, __HIP_MEMORY_SCOPE_AGENT) < tgt) {
        __builtin_amdgcn_s_sleep(2);
        if (++spins > (1 << 22)) break;
    }
}

__global__ __launch_bounds__(640, 3)   // VGPR cap ~170: keeps wv+wv2 resident
void gru_fused(const float* __restrict__ xg0,      // (B,S,300) precomputed
               const float* __restrict__ w_hh0, const float* __restrict__ b_hh0,
               const float* __restrict__ w_ih1, const float* __restrict__ b_ih1,
               const float* __restrict__ w_hh1, const float* __restrict__ b_hh1,
               const float* __restrict__ w_out, const float* __restrict__ b_out,
               const float* __restrict__ h_init, // (2,B,100)
               float* __restrict__ ring,          // (B, RING_W, 300)
               int* prog0, int* cons1,            // 64*32 ints each
               float* __restrict__ out,           // (B,S,98)
               int S)
{
    __shared__ __align__(16) float hs[2][104];    // double-buffered h state

    const int tid   = threadIdx.x;
    const int layer = blockIdx.x >> 6;   // 0 producer / 1 consumer
    const int b     = blockIdx.x & 63;

    // ---- dot1 lane mapping: wave w, lanes 6*jl+{0..5} -> j = 10w+jl ------
    const int lane  = tid & 63;
    const int wid   = tid >> 6;          // 0..9
    const int pair  = lane >> 1;         // 0..31
    const int jl    = pair / 3;          // 0..10 (10 = pad lanes 60..63)
    const int role  = pair - 3 * jl;     // 0=r 1=z 2=n
    const int halfd = tid & 1;           // k-half (0: k<48, 1: k>=48)
    const int j     = wid * 10 + jl;     // h index
    const bool d1   = (lane < 60);
    const bool evenl= d1 && (halfd == 0);
    const bool gate = evenl && (role == 0);
    const bool loadA= evenl && (role <= 1);
    const int jc    = (j < 100) ? j : 99;
    const int row1  = role * 100 + jc;   // w_hh row (clamped for pad lanes)

    // ---- dot2 mapping (plain): pair g2 = tid>>1 owns row g2 --------------
    const int g2    = tid >> 1;
    const int n2    = layer ? 98 : 300;
    const bool act2 = (g2 < n2);
    const int g2c   = act2 ? g2 : 0;

    int* myprog = prog0 + b * 32;
    int* mycons = cons1 + b * 32;

    const float* w_hh = layer ? w_hh1 : w_hh0;
    const float* W2   = layer ? w_out : w_ih1;

    float4 wv[13], wv2[13];
    {
        const float* p = w_hh + row1 * 100 + halfd * 48;   // 16B aligned
        #pragma unroll
        for (int i = 0; i < 13; i++) wv[i] = *(const float4*)(p + 4 * i);
        if (!halfd) wv[12] = make_float4(0.f, 0.f, 0.f, 0.f);
        const float* q = W2 + g2c * 100 + halfd * 48;
        #pragma unroll
        for (int i = 0; i < 13; i++) wv2[i] = *(const float4*)(q + 4 * i);
        if (!halfd) wv2[12] = make_float4(0.f, 0.f, 0.f, 0.f);
    }
    const float bhh   = (layer ? b_hh1 : b_hh0)[row1];
    const float bias2 = (layer ? b_out : b_ih1)[g2c];

    float hcur = 0.f;
    if (gate) hcur = h_init[layer * 6400 + b * 100 + j];
    if (tid < 100) hs[0][tid] = h_init[layer * 6400 + b * 100 + tid];

    float* ringb      = ring + (size_t)b * RING_W * 300;
    const float* xgb  = xg0 + (size_t)b * (size_t)S * 300;
    float* outb       = out + (size_t)b * (size_t)S * 98;

    float xA_n = 0.f, xN_n = 0.f;    // prefetched x gate inputs (next step)

    if (layer == 0) {
        if (loadA) xA_n = xgb[row1];          // xr / xz for t=0
        if (gate)  xN_n = xgb[200 + j];       // xn for t=0
    } else {
        // cover pre-loop prefetch (slot 0) + window iters 0..15 (slots <=16)
        if (tid == 0) wait_ge(myprog, (S < KPUB + 1) ? S : (KPUB + 1));
    }
    __syncthreads();
    if (layer == 1) {
        if (loadA) xA_n = ringb[row1];
        if (gate)  xN_n = ringb[200 + j];
    }

    for (int t = 0; t < S; t++) {
        const int cur = t & 1;
        const int nxt = cur ^ 1;
        const float xA = xA_n, xN = xN_n;

        // prefetch x for step t+1 (load stays in flight across the barrier)
        if (t + 1 < S) {
            const float* src = (layer == 0)
                ? xgb + (size_t)(t + 1) * 300
                : ringb + (size_t)((t + 1) & (RING_W - 1)) * 300;
            if (loadA) xA_n = src[row1];
            if (gate)  xN_n = src[200 + j];
        }

        // ---- dot1: w_hh[row1] . h_{t-1} (hs[cur]) ------------------------
        const float4* h4p = (const float4*)hs[cur];
        const int base = halfd * 12;
        float a0 = 0.f, a1 = 0.f, a2 = 0.f, a3 = 0.f;
        #pragma unroll
        for (int i = 0; i < 13; i++) {
            const float4 h4 = h4p[base + i];
            const float4 w = wv[i];
            a0 += w.x * h4.x; a1 += w.y * h4.y;
            a2 += w.z * h4.z; a3 += w.w * h4.w;
        }
        float tot = (a0 + a2) + (a1 + a3);
        tot += __shfl_down(tot, 1);          // even lane: full dot
        float val = tot + bhh;               // hg (r/z/n row)
        if (loadA) val += xA;                // roles r,z: add x part
        const float zpre = __shfl(val, lane + 2);   // from role z lane
        const float hnv  = __shfl(val, lane + 4);   // from role n lane (no x)

        if (gate) {                          // lane 6*jl: full gate, in-reg
            const float r = fsig(val);
            const float z = fsig(zpre);
            const float n = ftanh(xN + r * hnv);
            hcur = (1.f - z) * n + z * hcur;
            hs[nxt][j] = hcur;
        }

        // ---- dot2 on the STABLE buffer (h_{t-1}): slot/row t-1 -----------
        if (act2 && t > 0) {
            float c0 = 0.f, c1 = 0.f, c2 = 0.f, c3 = 0.f;
            #pragma unroll
            for (int i = 0; i < 13; i++) {
                const float4 h4 = h4p[base + i];
                const float4 w = wv2[i];
                c0 += w.x * h4.x; c1 += w.y * h4.y;
                c2 += w.z * h4.z; c3 += w.w * h4.w;
            }
            float tot2 = (c0 + c2) + (c1 + c3);
            tot2 += __shfl_down(tot2, 1);
            if (!halfd) {
                if (layer == 0)
                    ringb[(size_t)((t - 1) & (RING_W - 1)) * 300 + g2] = tot2 + bias2;
                else
                    outb[(size_t)(t - 1) * 98 + g2] = tot2 + bias2;
            }
        }

        // ---- single barrier + flag protocol ------------------------------
        if (((t + 1) & (KPUB - 1)) == 0) {
            if (layer == 0) {
                bar_full();   // drains ring stores of slots <= t-1
                if (tid == 0) {
                    __hip_atomic_store(myprog, t, __ATOMIC_RELEASE, __HIP_MEMORY_SCOPE_AGENT);
                    const int need = t - 240;         // ring back-pressure
                    if (need > 0) wait_ge(mycons, need);
                }
            } else {
                if (tid == 0) {
                    __hip_atomic_store(mycons, t, __ATOMIC_RELEASE, __HIP_MEMORY_SCOPE_AGENT);
                    int tgt = t + 2 + KPUB;           // covers prefetch <= slot t+1+KPUB
                    if (tgt > S) tgt = S;
                    wait_ge(myprog, tgt);             // BEFORE barrier: no prefetch race
                }
                bar_lgkm();
            }
        } else {
            bar_lgkm();
        }
    }

    // ---- final dot2 for h_{S-1} (in hs[S&1]) -----------------------------
    {
        const float4* h4p = (const float4*)hs[S & 1];
        const int base = halfd * 12;
        if (act2) {
            float c0 = 0.f, c1 = 0.f, c2 = 0.f, c3 = 0.f;
            #pragma unroll
            for (int i = 0; i < 13; i++) {
                const float4 h4 = h4p[base + i];
                const float4 w = wv2[i];
                c0 += w.x * h4.x; c1 += w.y * h4.y;
                c2 += w.z * h4.z; c3 += w.w * h4.w;
            }
            float tot2 = (c0 + c2) + (c1 + c3);
            tot2 += __shfl_down(tot2, 1);
            if (!halfd) {
                if (layer == 0)
                    ringb[(size_t)((S - 1) & (RING_W - 1)) * 300 + g2] = tot2 + bias2;
                else
                    outb[(size_t)(S - 1) * 98 + g2] = tot2 + bias2;
            }
        }
    }
    if (layer == 0) {
        bar_full();          // drain slot S-1
        if (tid == 0)
            __hip_atomic_store(myprog, S, __ATOMIC_RELEASE, __HIP_MEMORY_SCOPE_AGENT);
    }
}

// ---------------------------------------------------------------------------

extern "C" void kernel_launch(void* const* d_in, const int* in_sizes, int n_in,
                              void* d_out, int out_size, void* d_ws, size_t ws_size,
                              hipStream_t stream)
{
    const float* seq    = (const float*)d_in[0];
    const float* h0     = (const float*)d_in[1];   // (2, 64, 100)
    const float* w_ih0  = (const float*)d_in[2];   // (300, 208)
    const float* w_hh0  = (const float*)d_in[3];   // (300, 100)
    const float* b_ih0  = (const float*)d_in[4];
    const float* b_hh0  = (const float*)d_in[5];
    const float* w_ih1  = (const float*)d_in[6];   // (300, 100)
    const float* w_hh1  = (const float*)d_in[7];
    const float* b_ih1  = (const float*)d_in[8];
    const float* b_hh1  = (const float*)d_in[9];
    const float* w_out  = (const float*)d_in[10];  // (98, 100)
    const float* b_out  = (const float*)d_in[11];
    float* out = (float*)d_out;

    const int B = 64, S = 2048, IN = 208, G = 300;

    // workspace: flags (2 * 64*32 ints) | xg0 (B,S,300) | ring (B,RING_W,300)
    int* prog0 = (int*)d_ws;
    int* cons1 = prog0 + 64 * 32;
    float* xg0 = (float*)(cons1 + 64 * 32);
    float* ringbuf = xg0 + (size_t)B * S * G;

    hipMemsetAsync(d_ws, 0, 2 * 64 * 32 * sizeof(int), stream);

    // xg0 = seq @ w_ih0^T + b_ih0   (full S in one pass)
    const dim3 blk(256);
    const dim3 gX((B * S) / GB_BM, (G + GB_BN - 1) / GB_BN);   // (2048, 5)
    gemm_bias<<<gX, blk, 0, stream>>>(seq, w_ih0, b_ih0, xg0,
                                      S, (long)S * IN, (long)IN,
                                      (long)S * G, (long)G, G, IN);

    // fused persistent 2-layer scan + projections
    gru_fused<<<dim3(128), dim3(640), 0, stream>>>(
        xg0, w_hh0, b_hh0, w_ih1, b_ih1, w_hh1, b_hh1, w_out, b_out,
        h0, ringbuf, prog0, cons1, out, S);
}